// Round 6
// baseline (1603.618 us; speedup 1.0000x reference)
//
#include <hip/hip_runtime.h>

#define NNODES 100000
#define NEDGES 1600000
#define D 64
#define EPSN 1e-12f
#define NBUK ((NNODES + 255) >> 8)   // 391 buckets of 256 nodes
#define NSLICE 64                    // contention-spreading sub-counters
#define CAPS 128                     // per-(bucket,slice) capacity (mean 64)

// ---------------------------------------------------------------------------
// P1: bucket scatter. bucket = dst>>8; slice = blockIdx&63 spreads the
// atomic counter 64-way.  Packed value = (src<<8) | (dst&255).
// ---------------------------------------------------------------------------
__global__ __launch_bounds__(256) void bucket_scatter_kernel(
    const int* __restrict__ src,
    const int* __restrict__ dst,
    int* __restrict__ bukcur,
    int* __restrict__ ebuf)
{
    const int e = blockIdx.x * 256 + threadIdx.x;
    if (e >= NEDGES) return;
    const int d = dst[e];
    const int b = d >> 8;
    const int slice = blockIdx.x & (NSLICE - 1);
    const int c = b * NSLICE + slice;
    const int p = atomicAdd(&bukcur[c], 1);
    if (p < CAPS) ebuf[((size_t)c << 7) + p] = (src[e] << 8) | (d & 255);
}

// ---------------------------------------------------------------------------
// Fused bucket aggregate: one block per bucket keeps the bucket's 256 agg
// rows in LDS (plane layout al[j][256][16] for mild bank conflicts), walks
// the bucket's 64 slice lists, gathers x[src] rows with quarter-wave float4
// loads, and ds_add_f32-accumulates into LDS.  Replaces place+gather; no
// rowptr/ssrc needed at all.
// ---------------------------------------------------------------------------
__global__ __launch_bounds__(256) void bucket_agg_kernel(
    const float* __restrict__ xin,
    const int* __restrict__ bukcur,
    const int* __restrict__ ebuf,
    float* __restrict__ agg)
{
    __shared__ float al[4 * 4096];   // plane j: [256 rows][16 f-slots] = 64KB
    const int b = blockIdx.x;
    const int t = threadIdx.x;

    float4* al4 = reinterpret_cast<float4*>(al);
    for (int i = t; i < 4096; i += 256) al4[i] = make_float4(0.f, 0.f, 0.f, 0.f);
    __syncthreads();

    const int w    = t >> 6;    // wave 0..3 (handles 16 slices)
    const int lane = t & 63;
    const int g    = lane >> 4; // entry subgroup 0..3
    const int f    = lane & 15; // float4 slot

    for (int s16 = 0; s16 < 16; ++s16) {
        const int sl  = w * 16 + s16;
        const int c   = b * NSLICE + sl;
        const int cnt = min(bukcur[c], CAPS);
        const int* eb = ebuf + ((size_t)c << 7);
        const int pvA = eb[lane];        // slots 0..63   (coalesced)
        const int pvB = eb[64 + lane];   // slots 64..127

        const int limA = min(cnt, 64);
        #pragma unroll 4
        for (int k = 0; k < limA; k += 4) {
            const int pv = __shfl(pvA, k + g, 64);
            if (k + g < limA) {
                const int s = pv >> 8, d = pv & 255;
                const float4 v = *reinterpret_cast<const float4*>(
                    &xin[(size_t)s * D + f * 4]);
                atomicAdd(&al[0 * 4096 + d * 16 + f], v.x);
                atomicAdd(&al[1 * 4096 + d * 16 + f], v.y);
                atomicAdd(&al[2 * 4096 + d * 16 + f], v.z);
                atomicAdd(&al[3 * 4096 + d * 16 + f], v.w);
            }
        }
        const int limB = cnt - 64;
        #pragma unroll 4
        for (int k = 0; k < limB; k += 4) {
            const int pv = __shfl(pvB, k + g, 64);
            if (k + g < limB) {
                const int s = pv >> 8, d = pv & 255;
                const float4 v = *reinterpret_cast<const float4*>(
                    &xin[(size_t)s * D + f * 4]);
                atomicAdd(&al[0 * 4096 + d * 16 + f], v.x);
                atomicAdd(&al[1 * 4096 + d * 16 + f], v.y);
                atomicAdd(&al[2 * 4096 + d * 16 + f], v.z);
                atomicAdd(&al[3 * 4096 + d * 16 + f], v.w);
            }
        }
    }
    __syncthreads();

    // write out the bucket's agg rows (coalesced float4, conflict-free reads)
    const int base = b * 256;
    for (int ii = t; ii < 4096; ii += 256) {
        const int row = ii >> 4, f4 = ii & 15;
        const int node = base + row;
        if (node < NNODES) {
            float4 o;
            o.x = al[0 * 4096 + row * 16 + f4];
            o.y = al[1 * 4096 + row * 16 + f4];
            o.z = al[2 * 4096 + row * 16 + f4];
            o.w = al[3 * 4096 + row * 16 + f4];
            *reinterpret_cast<float4*>(&agg[(size_t)node * D + f4 * 4]) = o;
        }
    }
}

// ---------------------------------------------------------------------------
// Transform: out[n][o] = bias[o] + sum_k agg[n][k]*Wl[o][k] + xin[n][k]*Wr[o][k]
// One wave per block; lane o holds Wl[o][:], Wr[o][:] in 128 registers.
// ---------------------------------------------------------------------------
template <bool RELU_NORM>
__global__ __launch_bounds__(64, 2) void transform_kernel(
    const float* __restrict__ agg,
    const float* __restrict__ xin,
    const float* __restrict__ Wl,
    const float* __restrict__ bl,
    const float* __restrict__ Wr,
    float* __restrict__ out)
{
    __shared__ float rowbuf[2][D];
    const int lane = threadIdx.x;

    float wl[D], wr[D];
    #pragma unroll
    for (int kb = 0; kb < 16; ++kb) {
        const float4 a = *reinterpret_cast<const float4*>(&Wl[lane * D + kb * 4]);
        const float4 b = *reinterpret_cast<const float4*>(&Wr[lane * D + kb * 4]);
        wl[kb * 4 + 0] = a.x; wl[kb * 4 + 1] = a.y;
        wl[kb * 4 + 2] = a.z; wl[kb * 4 + 3] = a.w;
        wr[kb * 4 + 0] = b.x; wr[kb * 4 + 1] = b.y;
        wr[kb * 4 + 2] = b.z; wr[kb * 4 + 3] = b.w;
    }
    const float bias = bl[lane];

    for (int node = blockIdx.x; node < NNODES; node += gridDim.x) {
        if (lane < 16) {
            *reinterpret_cast<float4*>(&rowbuf[0][lane * 4]) =
                *reinterpret_cast<const float4*>(&agg[(size_t)node * D + lane * 4]);
        } else if (lane < 32) {
            const int f = lane & 15;
            *reinterpret_cast<float4*>(&rowbuf[1][f * 4]) =
                *reinterpret_cast<const float4*>(&xin[(size_t)node * D + f * 4]);
        }
        __syncthreads();

        float oacc = bias;
        #pragma unroll
        for (int kb = 0; kb < 16; ++kb) {
            const float4 a  = *reinterpret_cast<const float4*>(&rowbuf[0][kb * 4]);
            const float4 xv = *reinterpret_cast<const float4*>(&rowbuf[1][kb * 4]);
            oacc += a.x  * wl[kb * 4 + 0] + a.y  * wl[kb * 4 + 1]
                  + a.z  * wl[kb * 4 + 2] + a.w  * wl[kb * 4 + 3];
            oacc += xv.x * wr[kb * 4 + 0] + xv.y * wr[kb * 4 + 1]
                  + xv.z * wr[kb * 4 + 2] + xv.w * wr[kb * 4 + 3];
        }
        if (RELU_NORM) {
            oacc = fmaxf(oacc, 0.f);
            float ss = oacc * oacc;
            #pragma unroll
            for (int m = 1; m < 64; m <<= 1) ss += __shfl_xor(ss, m, 64);
            oacc = oacc / fmaxf(sqrtf(ss), EPSN);
        }
        out[(size_t)node * D + lane] = oacc;
        __syncthreads();
    }
}

extern "C" void kernel_launch(void* const* d_in, const int* in_sizes, int n_in,
                              void* d_out, int out_size, void* d_ws, size_t ws_size,
                              hipStream_t stream) {
    const float* x   = (const float*)d_in[0];
    const int* eidx  = (const int*)d_in[1];
    // d_in[2] = edge_feature (unused)
    const float* W1l = (const float*)d_in[3];
    const float* b1l = (const float*)d_in[4];
    const float* W1r = (const float*)d_in[5];
    const float* W2l = (const float*)d_in[6];
    const float* b2l = (const float*)d_in[7];
    const float* W2r = (const float*)d_in[8];
    float* out = (float*)d_out;

    const int* src = eidx;            // edge_index[0]
    const int* dst = eidx + NEDGES;   // edge_index[1]

    // workspace layout (16B-aligned chunks)
    char* ws = (char*)d_ws;
    int* bukcur = (int*)ws;  ws += ((size_t)NBUK * NSLICE * 4 + 15) / 16 * 16;
    int* ebuf   = (int*)ws;  ws += ((size_t)NBUK * NSLICE * CAPS * 4 + 15) / 16 * 16;
    float* agg  = (float*)ws;                  // [N, D]
    float* h    = out;                         // layer-1 output lives in d_out

    dim3 blk(256);
    dim3 egrid((NEDGES + 255) / 256);
    dim3 tgrid(4096);
    dim3 tblk(64);

    // ---- bucket build (shared by both layers) ----
    hipMemsetAsync(bukcur, 0, (size_t)NBUK * NSLICE * 4, stream);
    bucket_scatter_kernel<<<egrid, blk, 0, stream>>>(src, dst, bukcur, ebuf);

    // ---- layer 1: h = normalize(relu(agg@W1l^T + b1l + x@W1r^T)) ----
    bucket_agg_kernel<<<NBUK, blk, 0, stream>>>(x, bukcur, ebuf, agg);
    transform_kernel<true><<<tgrid, tblk, 0, stream>>>(agg, x, W1l, b1l, W1r, h);

    // ---- layer 2: out = agg(h)@W2l^T + b2l + h@W2r^T ----
    bucket_agg_kernel<<<NBUK, blk, 0, stream>>>(h, bukcur, ebuf, agg);
    transform_kernel<false><<<tgrid, tblk, 0, stream>>>(agg, h, W2l, b2l, W2r, out);
}

// Round 7
// 308.361 us; speedup vs baseline: 5.2005x; 5.2005x over previous
//
#include <hip/hip_runtime.h>

#define NNODES 100000
#define NEDGES 1600000
#define D 64
#define EPSN 1e-12f
#define NBUK ((NNODES + 255) >> 8)   // 391 buckets of 256 nodes
#define EPB 2048                     // edges per binning block
#define LCAP 28                      // per-(block,bucket) LDS capacity (mean 5.2)
#define BUKCAP 4608                  // per-bucket global capacity (mean 4092, sd 64)

// ---------------------------------------------------------------------------
// P1: LDS-binned scatter.  Each block bins 2048 edges into 391 LDS bucket
// lists (LDS atomics), then reserves space per bucket with ONE global
// atomicAdd per non-empty (block,bucket) and copies the run out.  Global
// atomics: 1.6M -> ~0.3M (the round-5 TCC atomic-throughput wall).
// ebuf ends up compactly packed per bucket.  Packed val = (src<<8)|(dst&255).
// ---------------------------------------------------------------------------
__global__ __launch_bounds__(256) void bin_scatter_kernel(
    const int* __restrict__ src,
    const int* __restrict__ dst,
    int* __restrict__ bukcnt,
    int* __restrict__ ebuf)
{
    __shared__ int lcnt[NBUK];
    __shared__ int bins[NBUK * LCAP];   // 391*28 ints = 43.8 KB
    const int t = threadIdx.x;
    for (int i = t; i < NBUK; i += 256) lcnt[i] = 0;
    __syncthreads();

    const long long e0 = (long long)blockIdx.x * EPB + (long long)t * 8;
    if (e0 + 8 <= NEDGES) {
        const int4 sa = *reinterpret_cast<const int4*>(&src[e0]);
        const int4 sb = *reinterpret_cast<const int4*>(&src[e0 + 4]);
        const int4 da = *reinterpret_cast<const int4*>(&dst[e0]);
        const int4 db = *reinterpret_cast<const int4*>(&dst[e0 + 4]);
        const int dd[8] = {da.x, da.y, da.z, da.w, db.x, db.y, db.z, db.w};
        const int ss[8] = {sa.x, sa.y, sa.z, sa.w, sb.x, sb.y, sb.z, sb.w};
        #pragma unroll
        for (int i = 0; i < 8; ++i) {
            const int b = dd[i] >> 8;
            const int p = atomicAdd(&lcnt[b], 1);
            if (p < LCAP) bins[b * LCAP + p] = (ss[i] << 8) | (dd[i] & 255);
        }
    } else {
        for (long long e = e0; e < NEDGES; ++e) {
            const int d = dst[e];
            const int b = d >> 8;
            const int p = atomicAdd(&lcnt[b], 1);
            if (p < LCAP) bins[b * LCAP + p] = (src[e] << 8) | (d & 255);
        }
    }
    __syncthreads();

    // one global atomic per non-empty bucket; copy the run compactly
    for (int b = t; b < NBUK; b += 256) {
        const int cnt = min(lcnt[b], LCAP);
        if (cnt == 0) continue;
        const int base = atomicAdd(&bukcnt[b], cnt);
        for (int i = 0; i < cnt; ++i) {
            const int p = base + i;
            if (p < BUKCAP) ebuf[(size_t)b * BUKCAP + p] = bins[b * LCAP + i];
        }
    }
}

// ---------------------------------------------------------------------------
// Exclusive scan over the 391 bucket counts -> bucket start offsets.
// ---------------------------------------------------------------------------
__global__ void bukscan_kernel(const int* __restrict__ bukcnt,
                               int* __restrict__ bukstart) {
    __shared__ int s[512];
    const int t = threadIdx.x;
    const int v = (t < NBUK) ? min(bukcnt[t], BUKCAP) : 0;
    int val = v;
    s[t] = val;
    __syncthreads();
    for (int off = 1; off < 512; off <<= 1) {
        int add = (t >= off) ? s[t - off] : 0;
        __syncthreads();
        val += add;
        s[t] = val;
        __syncthreads();
    }
    if (t < NBUK) bukstart[t] = val - v;   // exclusive
}

// ---------------------------------------------------------------------------
// P2: per-bucket placement from the COMPACT list.  LDS count + scan of the
// bucket's 256 nodes gives rowptr; LDS cursors place srcs into a contiguous
// CSR window.
// ---------------------------------------------------------------------------
__global__ __launch_bounds__(256) void bucket_place_kernel(
    const int* __restrict__ bukcnt,
    const int* __restrict__ bukstart,
    const int* __restrict__ ebuf,
    int* __restrict__ rowptr,
    int* __restrict__ ssrc)
{
    __shared__ int lcnt[256];   // counts -> exclusive offsets
    __shared__ int lcur[256];   // placement cursors
    __shared__ int stmp[256];   // scan temp
    const int b = blockIdx.x;
    const int t = threadIdx.x;
    lcnt[t] = 0;
    lcur[t] = 0;
    __syncthreads();

    const int cnt  = min(bukcnt[b], BUKCAP);
    const int base = bukstart[b];
    const int* eb  = ebuf + (size_t)b * BUKCAP;

    for (int i = t; i < cnt; i += 256) atomicAdd(&lcnt[eb[i] & 255], 1);
    __syncthreads();

    const int v = lcnt[t];
    int val = v;
    stmp[t] = val;
    __syncthreads();
    for (int off = 1; off < 256; off <<= 1) {
        int add = (t >= off) ? stmp[t - off] : 0;
        __syncthreads();
        val += add;
        stmp[t] = val;
        __syncthreads();
    }
    const int myoff = val - v;
    __syncthreads();
    lcnt[t] = myoff;             // repurpose as offsets
    const int node = b * 256 + t;
    if (node < NNODES) rowptr[node] = base + myoff;
    if (b == NBUK - 1 && t == 0) rowptr[NNODES] = base + cnt;
    __syncthreads();

    for (int i = t; i < cnt; i += 256) {
        const int pv = eb[i];
        const int d = pv & 255;
        const int p = atomicAdd(&lcur[d], 1);
        ssrc[base + lcnt[d] + p] = pv >> 8;
    }
}

// ---------------------------------------------------------------------------
// Gather: agg[n] = sum_{s in row(n)} feat[s].  Quarter-wave (16 lanes) per
// node, float4 per lane => one 256B coalesced request per edge-row.
// Tiny VGPR/LDS footprint -> max occupancy -> max memory-level parallelism.
// ---------------------------------------------------------------------------
__global__ __launch_bounds__(256) void gather_kernel(
    const float* __restrict__ feat,
    const int* __restrict__ rowptr,
    const int* __restrict__ ssrc,
    float* __restrict__ agg)
{
    const int tid = threadIdx.x;
    const int quarter = tid >> 4;            // 0..15
    const int f = tid & 15;                  // float4 slot within row
    const int node = blockIdx.x * 16 + quarter;
    if (node >= NNODES) return;

    const int beg = rowptr[node];
    const int end = rowptr[node + 1];
    const float* fb = feat + (size_t)f * 4;

    float ax = 0.f, ay = 0.f, az = 0.f, aw = 0.f;
    int j = beg;
    for (; j + 4 <= end; j += 4) {
        const int s0 = ssrc[j + 0];
        const int s1 = ssrc[j + 1];
        const int s2 = ssrc[j + 2];
        const int s3 = ssrc[j + 3];
        const float4 v0 = *reinterpret_cast<const float4*>(&fb[(size_t)s0 * D]);
        const float4 v1 = *reinterpret_cast<const float4*>(&fb[(size_t)s1 * D]);
        const float4 v2 = *reinterpret_cast<const float4*>(&fb[(size_t)s2 * D]);
        const float4 v3 = *reinterpret_cast<const float4*>(&fb[(size_t)s3 * D]);
        ax += v0.x + v1.x + v2.x + v3.x;
        ay += v0.y + v1.y + v2.y + v3.y;
        az += v0.z + v1.z + v2.z + v3.z;
        aw += v0.w + v1.w + v2.w + v3.w;
    }
    for (; j < end; ++j) {
        const int s = ssrc[j];
        const float4 v = *reinterpret_cast<const float4*>(&fb[(size_t)s * D]);
        ax += v.x; ay += v.y; az += v.z; aw += v.w;
    }
    float4 r; r.x = ax; r.y = ay; r.z = az; r.w = aw;
    *reinterpret_cast<float4*>(&agg[(size_t)node * D + f * 4]) = r;
}

// ---------------------------------------------------------------------------
// Transform: out[n][o] = bias[o] + sum_k agg[n][k]*Wl[o][k] + xin[n][k]*Wr[o][k]
// One wave per block; lane o holds Wl[o][:], Wr[o][:] in 128 registers.
// ---------------------------------------------------------------------------
template <bool RELU_NORM>
__global__ __launch_bounds__(64, 2) void transform_kernel(
    const float* __restrict__ agg,
    const float* __restrict__ xin,
    const float* __restrict__ Wl,
    const float* __restrict__ bl,
    const float* __restrict__ Wr,
    float* __restrict__ out)
{
    __shared__ float rowbuf[2][D];
    const int lane = threadIdx.x;

    float wl[D], wr[D];
    #pragma unroll
    for (int kb = 0; kb < 16; ++kb) {
        const float4 a = *reinterpret_cast<const float4*>(&Wl[lane * D + kb * 4]);
        const float4 b = *reinterpret_cast<const float4*>(&Wr[lane * D + kb * 4]);
        wl[kb * 4 + 0] = a.x; wl[kb * 4 + 1] = a.y;
        wl[kb * 4 + 2] = a.z; wl[kb * 4 + 3] = a.w;
        wr[kb * 4 + 0] = b.x; wr[kb * 4 + 1] = b.y;
        wr[kb * 4 + 2] = b.z; wr[kb * 4 + 3] = b.w;
    }
    const float bias = bl[lane];

    for (int node = blockIdx.x; node < NNODES; node += gridDim.x) {
        if (lane < 16) {
            *reinterpret_cast<float4*>(&rowbuf[0][lane * 4]) =
                *reinterpret_cast<const float4*>(&agg[(size_t)node * D + lane * 4]);
        } else if (lane < 32) {
            const int f = lane & 15;
            *reinterpret_cast<float4*>(&rowbuf[1][f * 4]) =
                *reinterpret_cast<const float4*>(&xin[(size_t)node * D + f * 4]);
        }
        __syncthreads();

        float oacc = bias;
        #pragma unroll
        for (int kb = 0; kb < 16; ++kb) {
            const float4 a  = *reinterpret_cast<const float4*>(&rowbuf[0][kb * 4]);
            const float4 xv = *reinterpret_cast<const float4*>(&rowbuf[1][kb * 4]);
            oacc += a.x  * wl[kb * 4 + 0] + a.y  * wl[kb * 4 + 1]
                  + a.z  * wl[kb * 4 + 2] + a.w  * wl[kb * 4 + 3];
            oacc += xv.x * wr[kb * 4 + 0] + xv.y * wr[kb * 4 + 1]
                  + xv.z * wr[kb * 4 + 2] + xv.w * wr[kb * 4 + 3];
        }
        if (RELU_NORM) {
            oacc = fmaxf(oacc, 0.f);
            float ss = oacc * oacc;
            #pragma unroll
            for (int m = 1; m < 64; m <<= 1) ss += __shfl_xor(ss, m, 64);
            oacc = oacc / fmaxf(sqrtf(ss), EPSN);
        }
        out[(size_t)node * D + lane] = oacc;
        __syncthreads();
    }
}

extern "C" void kernel_launch(void* const* d_in, const int* in_sizes, int n_in,
                              void* d_out, int out_size, void* d_ws, size_t ws_size,
                              hipStream_t stream) {
    const float* x   = (const float*)d_in[0];
    const int* eidx  = (const int*)d_in[1];
    // d_in[2] = edge_feature (unused)
    const float* W1l = (const float*)d_in[3];
    const float* b1l = (const float*)d_in[4];
    const float* W1r = (const float*)d_in[5];
    const float* W2l = (const float*)d_in[6];
    const float* b2l = (const float*)d_in[7];
    const float* W2r = (const float*)d_in[8];
    float* out = (float*)d_out;

    const int* src = eidx;            // edge_index[0]
    const int* dst = eidx + NEDGES;   // edge_index[1]

    // workspace layout (16B-aligned chunks)
    char* ws = (char*)d_ws;
    int* bukcnt   = (int*)ws;  ws += ((size_t)NBUK * 4 + 15) / 16 * 16;
    int* bukstart = (int*)ws;  ws += ((size_t)NBUK * 4 + 15) / 16 * 16;
    int* rowptr   = (int*)ws;  ws += ((size_t)(NNODES + 1) * 4 + 15) / 16 * 16;
    int* ssrc     = (int*)ws;  ws += ((size_t)NEDGES * 4 + 15) / 16 * 16;
    int* ebuf     = (int*)ws;  ws += ((size_t)NBUK * BUKCAP * 4 + 15) / 16 * 16;
    float* agg    = (float*)ws;                // [N, D]
    float* h      = out;                       // layer-1 output lives in d_out

    dim3 blk(256);
    dim3 bgrid((NEDGES + EPB - 1) / EPB);      // 782
    dim3 ggrid((NNODES + 15) / 16);
    dim3 tgrid(4096);
    dim3 tblk(64);

    // ---- CSR build (shared by both layers) ----
    hipMemsetAsync(bukcnt, 0, (size_t)NBUK * 4, stream);
    bin_scatter_kernel<<<bgrid, blk, 0, stream>>>(src, dst, bukcnt, ebuf);
    bukscan_kernel<<<1, 512, 0, stream>>>(bukcnt, bukstart);
    bucket_place_kernel<<<NBUK, blk, 0, stream>>>(bukcnt, bukstart, ebuf,
                                                  rowptr, ssrc);

    // ---- layer 1: h = normalize(relu(agg@W1l^T + b1l + x@W1r^T)) ----
    gather_kernel<<<ggrid, blk, 0, stream>>>(x, rowptr, ssrc, agg);
    transform_kernel<true><<<tgrid, tblk, 0, stream>>>(agg, x, W1l, b1l, W1r, h);

    // ---- layer 2: out = agg(h)@W2l^T + b2l + h@W2r^T ----
    gather_kernel<<<ggrid, blk, 0, stream>>>(h, rowptr, ssrc, agg);
    transform_kernel<false><<<tgrid, tblk, 0, stream>>>(agg, h, W2l, b2l, W2r, out);
}

// Round 8
// 279.148 us; speedup vs baseline: 5.7447x; 1.1047x over previous
//
#include <hip/hip_runtime.h>

#define NNODES 100000
#define NEDGES 1600000
#define D 64
#define EPSN 1e-12f
#define NBUK ((NNODES + 255) >> 8)   // 391 buckets of 256 nodes
#define EPB 2048                     // edges per binning block
#define LCAP 28                      // per-(block,bucket) LDS capacity (mean 5.2)
#define BUKCAP 4608                  // per-bucket global capacity (mean 4092, sd 64)

// ---------------------------------------------------------------------------
// P1: LDS-binned scatter.  Each block bins 2048 edges into 391 LDS bucket
// lists (LDS atomics), then reserves space per bucket with ONE global
// atomicAdd per non-empty (block,bucket) and copies the run out.
// ---------------------------------------------------------------------------
__global__ __launch_bounds__(256) void bin_scatter_kernel(
    const int* __restrict__ src,
    const int* __restrict__ dst,
    int* __restrict__ bukcnt,
    int* __restrict__ ebuf)
{
    __shared__ int lcnt[NBUK];
    __shared__ int bins[NBUK * LCAP];   // 391*28 ints = 43.8 KB
    const int t = threadIdx.x;
    for (int i = t; i < NBUK; i += 256) lcnt[i] = 0;
    __syncthreads();

    const long long e0 = (long long)blockIdx.x * EPB + (long long)t * 8;
    if (e0 + 8 <= NEDGES) {
        const int4 sa = *reinterpret_cast<const int4*>(&src[e0]);
        const int4 sb = *reinterpret_cast<const int4*>(&src[e0 + 4]);
        const int4 da = *reinterpret_cast<const int4*>(&dst[e0]);
        const int4 db = *reinterpret_cast<const int4*>(&dst[e0 + 4]);
        const int dd[8] = {da.x, da.y, da.z, da.w, db.x, db.y, db.z, db.w};
        const int ss[8] = {sa.x, sa.y, sa.z, sa.w, sb.x, sb.y, sb.z, sb.w};
        #pragma unroll
        for (int i = 0; i < 8; ++i) {
            const int b = dd[i] >> 8;
            const int p = atomicAdd(&lcnt[b], 1);
            if (p < LCAP) bins[b * LCAP + p] = (ss[i] << 8) | (dd[i] & 255);
        }
    } else {
        for (long long e = e0; e < NEDGES; ++e) {
            const int d = dst[e];
            const int b = d >> 8;
            const int p = atomicAdd(&lcnt[b], 1);
            if (p < LCAP) bins[b * LCAP + p] = (src[e] << 8) | (d & 255);
        }
    }
    __syncthreads();

    for (int b = t; b < NBUK; b += 256) {
        const int cnt = min(lcnt[b], LCAP);
        if (cnt == 0) continue;
        const int base = atomicAdd(&bukcnt[b], cnt);
        for (int i = 0; i < cnt; ++i) {
            const int p = base + i;
            if (p < BUKCAP) ebuf[(size_t)b * BUKCAP + p] = bins[b * LCAP + i];
        }
    }
}

// ---------------------------------------------------------------------------
// Exclusive scan over the 391 bucket counts -> bucket start offsets.
// ---------------------------------------------------------------------------
__global__ void bukscan_kernel(const int* __restrict__ bukcnt,
                               int* __restrict__ bukstart) {
    __shared__ int s[512];
    const int t = threadIdx.x;
    const int v = (t < NBUK) ? min(bukcnt[t], BUKCAP) : 0;
    int val = v;
    s[t] = val;
    __syncthreads();
    for (int off = 1; off < 512; off <<= 1) {
        int add = (t >= off) ? s[t - off] : 0;
        __syncthreads();
        val += add;
        s[t] = val;
        __syncthreads();
    }
    if (t < NBUK) bukstart[t] = val - v;   // exclusive
}

// ---------------------------------------------------------------------------
// P2: per-bucket placement from the COMPACT list -> rowptr + ssrc.
// ---------------------------------------------------------------------------
__global__ __launch_bounds__(256) void bucket_place_kernel(
    const int* __restrict__ bukcnt,
    const int* __restrict__ bukstart,
    const int* __restrict__ ebuf,
    int* __restrict__ rowptr,
    int* __restrict__ ssrc)
{
    __shared__ int lcnt[256];
    __shared__ int lcur[256];
    __shared__ int stmp[256];
    const int b = blockIdx.x;
    const int t = threadIdx.x;
    lcnt[t] = 0;
    lcur[t] = 0;
    __syncthreads();

    const int cnt  = min(bukcnt[b], BUKCAP);
    const int base = bukstart[b];
    const int* eb  = ebuf + (size_t)b * BUKCAP;

    for (int i = t; i < cnt; i += 256) atomicAdd(&lcnt[eb[i] & 255], 1);
    __syncthreads();

    const int v = lcnt[t];
    int val = v;
    stmp[t] = val;
    __syncthreads();
    for (int off = 1; off < 256; off <<= 1) {
        int add = (t >= off) ? stmp[t - off] : 0;
        __syncthreads();
        val += add;
        stmp[t] = val;
        __syncthreads();
    }
    const int myoff = val - v;
    __syncthreads();
    lcnt[t] = myoff;
    const int node = b * 256 + t;
    if (node < NNODES) rowptr[node] = base + myoff;
    if (b == NBUK - 1 && t == 0) rowptr[NNODES] = base + cnt;
    __syncthreads();

    for (int i = t; i < cnt; i += 256) {
        const int pv = eb[i];
        const int d = pv & 255;
        const int p = atomicAdd(&lcur[d], 1);
        ssrc[base + lcnt[d] + p] = pv >> 8;
    }
}

// ---------------------------------------------------------------------------
// Gather: agg[n] = sum_{s in row(n)} feat[s].  Quarter-wave per node.
// ---------------------------------------------------------------------------
__global__ __launch_bounds__(256) void gather_kernel(
    const float* __restrict__ feat,
    const int* __restrict__ rowptr,
    const int* __restrict__ ssrc,
    float* __restrict__ agg)
{
    const int tid = threadIdx.x;
    const int quarter = tid >> 4;
    const int f = tid & 15;
    const int node = blockIdx.x * 16 + quarter;
    if (node >= NNODES) return;

    const int beg = rowptr[node];
    const int end = rowptr[node + 1];
    const float* fb = feat + (size_t)f * 4;

    float ax = 0.f, ay = 0.f, az = 0.f, aw = 0.f;
    int j = beg;
    for (; j + 4 <= end; j += 4) {
        const int s0 = ssrc[j + 0];
        const int s1 = ssrc[j + 1];
        const int s2 = ssrc[j + 2];
        const int s3 = ssrc[j + 3];
        const float4 v0 = *reinterpret_cast<const float4*>(&fb[(size_t)s0 * D]);
        const float4 v1 = *reinterpret_cast<const float4*>(&fb[(size_t)s1 * D]);
        const float4 v2 = *reinterpret_cast<const float4*>(&fb[(size_t)s2 * D]);
        const float4 v3 = *reinterpret_cast<const float4*>(&fb[(size_t)s3 * D]);
        ax += v0.x + v1.x + v2.x + v3.x;
        ay += v0.y + v1.y + v2.y + v3.y;
        az += v0.z + v1.z + v2.z + v3.z;
        aw += v0.w + v1.w + v2.w + v3.w;
    }
    for (; j < end; ++j) {
        const int s = ssrc[j];
        const float4 v = *reinterpret_cast<const float4*>(&fb[(size_t)s * D]);
        ax += v.x; ay += v.y; az += v.z; aw += v.w;
    }
    float4 r; r.x = ax; r.y = ay; r.z = az; r.w = aw;
    *reinterpret_cast<float4*>(&agg[(size_t)node * D + f * 4]) = r;
}

// ---------------------------------------------------------------------------
// Transform v2: out[n][o] = bias[o] + agg[n]·Wl[o] + xin[n]·Wr[o].
// One wave per block.  Weights live in 32 NAMED float4 registers (no arrays
// -> allocator cannot demote them; launch_bounds(64,2) gives a 256-VGPR cap).
// 4 nodes per iteration: full-wave coalesced staging + 4-way ILP.
// ---------------------------------------------------------------------------
#define LW(i) \
    const float4 wl##i = *reinterpret_cast<const float4*>(&Wl[lane * D + i * 4]); \
    const float4 wr##i = *reinterpret_cast<const float4*>(&Wr[lane * D + i * 4]);

#define KSTEP(i) { \
    const float4 a0 = rb4[0][0][i]; const float4 q0 = rb4[0][1][i]; \
    const float4 a1 = rb4[1][0][i]; const float4 q1 = rb4[1][1][i]; \
    const float4 a2 = rb4[2][0][i]; const float4 q2 = rb4[2][1][i]; \
    const float4 a3 = rb4[3][0][i]; const float4 q3 = rb4[3][1][i]; \
    acc0 += a0.x*wl##i.x + a0.y*wl##i.y + a0.z*wl##i.z + a0.w*wl##i.w \
          + q0.x*wr##i.x + q0.y*wr##i.y + q0.z*wr##i.z + q0.w*wr##i.w; \
    acc1 += a1.x*wl##i.x + a1.y*wl##i.y + a1.z*wl##i.z + a1.w*wl##i.w \
          + q1.x*wr##i.x + q1.y*wr##i.y + q1.z*wr##i.z + q1.w*wr##i.w; \
    acc2 += a2.x*wl##i.x + a2.y*wl##i.y + a2.z*wl##i.z + a2.w*wl##i.w \
          + q2.x*wr##i.x + q2.y*wr##i.y + q2.z*wr##i.z + q2.w*wr##i.w; \
    acc3 += a3.x*wl##i.x + a3.y*wl##i.y + a3.z*wl##i.z + a3.w*wl##i.w \
          + q3.x*wr##i.x + q3.y*wr##i.y + q3.z*wr##i.z + q3.w*wr##i.w; }

template <bool RELU_NORM>
__global__ __launch_bounds__(64, 2) void transform_kernel(
    const float* __restrict__ agg,
    const float* __restrict__ xin,
    const float* __restrict__ Wl,
    const float* __restrict__ bl,
    const float* __restrict__ Wr,
    float* __restrict__ out)
{
    __shared__ float4 rb4[4][2][16];   // 4 nodes x {agg,x} x 64 floats = 2KB
    const int lane = threadIdx.x;

    LW(0)  LW(1)  LW(2)  LW(3)  LW(4)  LW(5)  LW(6)  LW(7)
    LW(8)  LW(9)  LW(10) LW(11) LW(12) LW(13) LW(14) LW(15)
    const float bias = bl[lane];

    const int i4 = lane >> 4;   // node-sub this lane stages
    const int f  = lane & 15;   // float4 slot

    const int stride = gridDim.x * 4;
    for (int n0 = blockIdx.x * 4; n0 < NNODES; n0 += stride) {
        // NNODES % 4 == 0 -> all 4 nodes valid
        rb4[i4][0][f] = *reinterpret_cast<const float4*>(
            &agg[(size_t)(n0 + i4) * D + f * 4]);
        rb4[i4][1][f] = *reinterpret_cast<const float4*>(
            &xin[(size_t)(n0 + i4) * D + f * 4]);
        __syncthreads();

        float acc0 = bias, acc1 = bias, acc2 = bias, acc3 = bias;
        KSTEP(0)  KSTEP(1)  KSTEP(2)  KSTEP(3)
        KSTEP(4)  KSTEP(5)  KSTEP(6)  KSTEP(7)
        KSTEP(8)  KSTEP(9)  KSTEP(10) KSTEP(11)
        KSTEP(12) KSTEP(13) KSTEP(14) KSTEP(15)

        if (RELU_NORM) {
            acc0 = fmaxf(acc0, 0.f); acc1 = fmaxf(acc1, 0.f);
            acc2 = fmaxf(acc2, 0.f); acc3 = fmaxf(acc3, 0.f);
            float s0 = acc0 * acc0, s1 = acc1 * acc1;
            float s2 = acc2 * acc2, s3 = acc3 * acc3;
            #pragma unroll
            for (int m = 1; m < 64; m <<= 1) {
                s0 += __shfl_xor(s0, m, 64);
                s1 += __shfl_xor(s1, m, 64);
                s2 += __shfl_xor(s2, m, 64);
                s3 += __shfl_xor(s3, m, 64);
            }
            acc0 /= fmaxf(sqrtf(s0), EPSN);
            acc1 /= fmaxf(sqrtf(s1), EPSN);
            acc2 /= fmaxf(sqrtf(s2), EPSN);
            acc3 /= fmaxf(sqrtf(s3), EPSN);
        }
        out[(size_t)(n0 + 0) * D + lane] = acc0;
        out[(size_t)(n0 + 1) * D + lane] = acc1;
        out[(size_t)(n0 + 2) * D + lane] = acc2;
        out[(size_t)(n0 + 3) * D + lane] = acc3;
        __syncthreads();
    }
}

extern "C" void kernel_launch(void* const* d_in, const int* in_sizes, int n_in,
                              void* d_out, int out_size, void* d_ws, size_t ws_size,
                              hipStream_t stream) {
    const float* x   = (const float*)d_in[0];
    const int* eidx  = (const int*)d_in[1];
    // d_in[2] = edge_feature (unused)
    const float* W1l = (const float*)d_in[3];
    const float* b1l = (const float*)d_in[4];
    const float* W1r = (const float*)d_in[5];
    const float* W2l = (const float*)d_in[6];
    const float* b2l = (const float*)d_in[7];
    const float* W2r = (const float*)d_in[8];
    float* out = (float*)d_out;

    const int* src = eidx;
    const int* dst = eidx + NEDGES;

    char* ws = (char*)d_ws;
    int* bukcnt   = (int*)ws;  ws += ((size_t)NBUK * 4 + 15) / 16 * 16;
    int* bukstart = (int*)ws;  ws += ((size_t)NBUK * 4 + 15) / 16 * 16;
    int* rowptr   = (int*)ws;  ws += ((size_t)(NNODES + 1) * 4 + 15) / 16 * 16;
    int* ssrc     = (int*)ws;  ws += ((size_t)NEDGES * 4 + 15) / 16 * 16;
    int* ebuf     = (int*)ws;  ws += ((size_t)NBUK * BUKCAP * 4 + 15) / 16 * 16;
    float* agg    = (float*)ws;                // [N, D]
    float* h      = out;                       // layer-1 output lives in d_out

    dim3 blk(256);
    dim3 bgrid((NEDGES + EPB - 1) / EPB);
    dim3 ggrid((NNODES + 15) / 16);
    dim3 tgrid(2048);
    dim3 tblk(64);

    // ---- CSR build (shared by both layers) ----
    hipMemsetAsync(bukcnt, 0, (size_t)NBUK * 4, stream);
    bin_scatter_kernel<<<bgrid, blk, 0, stream>>>(src, dst, bukcnt, ebuf);
    bukscan_kernel<<<1, 512, 0, stream>>>(bukcnt, bukstart);
    bucket_place_kernel<<<NBUK, blk, 0, stream>>>(bukcnt, bukstart, ebuf,
                                                  rowptr, ssrc);

    // ---- layer 1 ----
    gather_kernel<<<ggrid, blk, 0, stream>>>(x, rowptr, ssrc, agg);
    transform_kernel<true><<<tgrid, tblk, 0, stream>>>(agg, x, W1l, b1l, W1r, h);

    // ---- layer 2 ----
    gather_kernel<<<ggrid, blk, 0, stream>>>(h, rowptr, ssrc, agg);
    transform_kernel<false><<<tgrid, tblk, 0, stream>>>(agg, h, W2l, b2l, W2r, out);
}